// Round 3
// baseline (165.977 us; speedup 1.0000x reference)
//
#include <hip/hip_runtime.h>
#include <stdint.h>

// Problem constants (fixed by the reference)
#define B_      16
#define N_      2048
#define M_      8192
#define ROWS    (B_ * N_)        // 32768
#define D_      8                // 4*2 flattened

// Kernel A tiling
#define SPLITS  32               // anchor splits
#define MSPLIT  (M_ / SPLITS)    // 256 anchors per split
#define BLK     256              // threads per block
#define RPT     4                // rows per thread
#define ROWS_PER_BLK (BLK * RPT) // 1024
#define ROWBLKS (ROWS / ROWS_PER_BLK) // 32  -> grid 32x32 = 1024 blocks (4/CU)

// ws: float[SPLITS][ROWS] per-(split,row) min score = 4 MB. Every slot is
// written by kernel A (no init / no atomics needed).

// Kernel A: per (row, split) min score. Hot loop = 8 fmaf + 1 fmin per pair
// (exact-fp32 floor). Anchors staged NEGATED; 0.5*||a||^2 folded into the
// first fmaf's addend. No index tracking here.
__global__ __launch_bounds__(BLK) void argmin_part_kernel(
    const float* __restrict__ x,        // [ROWS][8]
    const float* __restrict__ anchors,  // [M_][8]
    float* __restrict__ ws)             // [SPLITS][ROWS]
{
    __shared__ float sA[MSPLIT * D_];   // 8 KB: negated anchor tile
    __shared__ float sH[MSPLIT];        // 1 KB: 0.5*||a||^2

    const int split = blockIdx.y;
    const int tid   = threadIdx.x;

    // Stage negated anchors: 256 anchors * 2 float4 = 512 float4
    const float4* gA = (const float4*)(anchors + (size_t)split * MSPLIT * D_);
    #pragma unroll
    for (int i = 0; i < 2; ++i) {
        const int k = tid + i * BLK;
        const float4 g = gA[k];
        ((float4*)sA)[k] = (float4){-g.x, -g.y, -g.z, -g.w};
    }
    __syncthreads();

    // Half-norms: EXACT chain replicated in kernel B (na*na == a*a exactly)
    {
        const float* na = &sA[tid * D_];
        float nr = na[0] * na[0];
        #pragma unroll
        for (int k = 1; k < D_; ++k) nr = fmaf(na[k], na[k], nr);
        sH[tid] = 0.5f * nr;
    }
    __syncthreads();

    // My RPT rows in registers (coalesced float4 loads)
    const int row0 = blockIdx.x * ROWS_PER_BLK + tid;
    float X[RPT][D_];
    #pragma unroll
    for (int r = 0; r < RPT; ++r) {
        const float4* px = (const float4*)(x + (size_t)(row0 + r * BLK) * D_);
        const float4 lo = px[0], hi = px[1];
        X[r][0] = lo.x; X[r][1] = lo.y; X[r][2] = lo.z; X[r][3] = lo.w;
        X[r][4] = hi.x; X[r][5] = hi.y; X[r][6] = hi.z; X[r][7] = hi.w;
    }

    float best[RPT];
    #pragma unroll
    for (int r = 0; r < RPT; ++r) best[r] = 3.4e38f;

    #pragma unroll 2
    for (int j = 0; j < MSPLIT; ++j) {
        const float4 a0 = ((const float4*)sA)[j * 2];     // LDS broadcast (free)
        const float4 a1 = ((const float4*)sA)[j * 2 + 1];
        const float  hn = sH[j];
        #pragma unroll
        for (int r = 0; r < RPT; ++r) {
            float s = fmaf(X[r][0], a0.x, hn);            // hn + sum x*(-a)
            s = fmaf(X[r][1], a0.y, s);
            s = fmaf(X[r][2], a0.z, s);
            s = fmaf(X[r][3], a0.w, s);
            s = fmaf(X[r][4], a1.x, s);
            s = fmaf(X[r][5], a1.y, s);
            s = fmaf(X[r][6], a1.z, s);
            s = fmaf(X[r][7], a1.w, s);
            best[r] = fminf(best[r], s);
        }
    }

    #pragma unroll
    for (int r = 0; r < RPT; ++r)
        ws[(size_t)split * ROWS + (row0 + r * BLK)] = best[r];   // coalesced
}

// Kernel B: per row, pick winning split (strict '<' over ascending splits ->
// lowest split wins ties), re-scan that split with the bit-identical fmaf
// chain to find the FIRST matching anchor (== jnp.argmin tie-break), then
// produce the output.
__global__ __launch_bounds__(256) void refine_combine_kernel(
    const float* __restrict__ x,        // [ROWS][8]
    const float* __restrict__ anchors,  // [M_][8]
    const float* __restrict__ sa_tab,   // [1000]
    const float* __restrict__ sb_tab,   // [1000]
    const int*   __restrict__ t,        // [B_]
    const float* __restrict__ ws,       // [SPLITS][ROWS]
    float* __restrict__ out)            // [ROWS][8]
{
    const int r = blockIdx.x * blockDim.x + threadIdx.x;

    // Reduce over splits (coalesced loads per split)
    float bs = ws[r];
    int   bsplit = 0;
    #pragma unroll
    for (int s = 1; s < SPLITS; ++s) {
        const float v = ws[(size_t)s * ROWS + r];
        const bool c = v < bs;
        bs     = c ? v : bs;
        bsplit = c ? s : bsplit;
    }
    const uint32_t target = __float_as_uint(bs);

    // My row
    const float4* px = (const float4*)(x + (size_t)r * D_);
    const float4 xlo = px[0], xhi = px[1];
    float X0 = xlo.x, X1 = xlo.y, X2 = xlo.z, X3 = xlo.w;
    float X4 = xhi.x, X5 = xhi.y, X6 = xhi.z, X7 = xhi.w;

    // Re-scan winning split; first bit-exact match wins
    const int base = bsplit * MSPLIT;
    int jb = 1 << 30;
    #pragma unroll 4
    for (int j = 0; j < MSPLIT; ++j) {
        const float4* pa = (const float4*)(anchors + (size_t)(base + j) * D_);
        const float4 g0 = pa[0], g1 = pa[1];
        const float na0 = -g0.x, na1 = -g0.y, na2 = -g0.z, na3 = -g0.w;
        const float na4 = -g1.x, na5 = -g1.y, na6 = -g1.z, na7 = -g1.w;
        // hn chain — identical to kernel A
        float nr = na0 * na0;
        nr = fmaf(na1, na1, nr);
        nr = fmaf(na2, na2, nr);
        nr = fmaf(na3, na3, nr);
        nr = fmaf(na4, na4, nr);
        nr = fmaf(na5, na5, nr);
        nr = fmaf(na6, na6, nr);
        nr = fmaf(na7, na7, nr);
        const float hn = 0.5f * nr;
        // score chain — identical to kernel A
        float s = fmaf(X0, na0, hn);
        s = fmaf(X1, na1, s);
        s = fmaf(X2, na2, s);
        s = fmaf(X3, na3, s);
        s = fmaf(X4, na4, s);
        s = fmaf(X5, na5, s);
        s = fmaf(X6, na6, s);
        s = fmaf(X7, na7, s);
        const bool m = (__float_as_uint(s) == target);
        jb = (m && j < jb) ? j : jb;          // keep FIRST match
    }
    jb = (jb > MSPLIT - 1) ? 0 : jb;          // defensive (cannot happen)
    const int bi = base + jb;

    const int b  = r >> 11;                   // r / N_
    const int tb = t[b];
    const float sa = sa_tab[tb];
    const float sb = sb_tab[tb];

    const float4* pa = (const float4*)(anchors + (size_t)bi * D_);
    const float4 a0 = pa[0], a1 = pa[1];

    float4 o0, o1;
    o0.x = fmaf(sa, xlo.x, sb * a0.x);
    o0.y = fmaf(sa, xlo.y, sb * a0.y);
    o0.z = fmaf(sa, xlo.z, sb * a0.z);
    o0.w = fmaf(sa, xlo.w, sb * a0.w);
    o1.x = fmaf(sa, xhi.x, sb * a1.x);
    o1.y = fmaf(sa, xhi.y, sb * a1.y);
    o1.z = fmaf(sa, xhi.z, sb * a1.z);
    o1.w = fmaf(sa, xhi.w, sb * a1.w);

    float4* po = (float4*)(out + (size_t)r * D_);
    po[0] = o0;
    po[1] = o1;
}

extern "C" void kernel_launch(void* const* d_in, const int* in_sizes, int n_in,
                              void* d_out, int out_size, void* d_ws, size_t ws_size,
                              hipStream_t stream) {
    const float* x       = (const float*)d_in[0];  // x_start [16,2048,4,2]
    const float* anchors = (const float*)d_in[1];  // anchors [8192,4,2]
    const float* sa_tab  = (const float*)d_in[2];  // sqrt_alphas_cumprod [1000]
    const float* sb_tab  = (const float*)d_in[3];  // sqrt_one_minus_alphas_cumprod [1000]
    const int*   t       = (const int*)d_in[4];    // t [16]
    float* out = (float*)d_out;

    float* ws = (float*)d_ws;   // [SPLITS][ROWS] = 4 MB, fully overwritten

    dim3 gridA(ROWBLKS, SPLITS);   // 32 x 32 = 1024 blocks
    argmin_part_kernel<<<gridA, BLK, 0, stream>>>(x, anchors, ws);

    refine_combine_kernel<<<ROWS / 256, 256, 0, stream>>>(
        x, anchors, sa_tab, sb_tab, t, ws, out);
}

// Round 4
// 125.019 us; speedup vs baseline: 1.3276x; 1.3276x over previous
//
#include <hip/hip_runtime.h>
#include <stdint.h>

// Problem constants (fixed by the reference)
#define B_      16
#define N_      2048
#define M_      8192
#define ROWS    (B_ * N_)        // 32768
#define D_      8                // 4*2 flattened

// Kernel A tiling
#define SPLITS  32               // anchor splits
#define MSPLIT  (M_ / SPLITS)    // 256 anchors per split
#define BLK     256              // threads per block
#define RPT     8                // rows per thread (amortizes LDS reads 8x -> VALU-bound)
#define ROWS_PER_BLK (BLK * RPT) // 2048
#define ROWBLKS (ROWS / ROWS_PER_BLK) // 16  -> grid 16x32 = 512 blocks

// Kernel B tiling
#define TPR     8                // threads per row
#define BROWS   32               // rows per block (256 threads)

// ws: float[SPLITS][ROWS] per-(split,row) min score = 4 MB. Every slot written
// by kernel A (no init, no atomics).

// Kernel A: per (row, split) min score. Hot loop = 8 fmaf + 1 fmin per pair
// (exact-fp32 floor; 18 cyc/pair/wave). Anchors staged NEGATED; 0.5*||a||^2
// folded into the first fmaf's addend. No index tracking here.
// RPT=8: per j-iter LDS = 2x ds_read_b128 + 1x b32 (~30 cyc) vs 144 VALU cyc
// -> LDS pipe at ~83% of capacity across 4 SIMDs, VALU is the critical pipe.
__global__ __launch_bounds__(BLK) void argmin_part_kernel(
    const float* __restrict__ x,        // [ROWS][8]
    const float* __restrict__ anchors,  // [M_][8]
    float* __restrict__ ws)             // [SPLITS][ROWS]
{
    __shared__ float sA[MSPLIT * D_];   // 8 KB: negated anchor tile
    __shared__ float sH[MSPLIT];        // 1 KB: 0.5*||a||^2

    const int split = blockIdx.y;
    const int tid   = threadIdx.x;

    // Stage negated anchors: 256 anchors * 2 float4 = 512 float4
    const float4* gA = (const float4*)(anchors + (size_t)split * MSPLIT * D_);
    #pragma unroll
    for (int i = 0; i < 2; ++i) {
        const int k = tid + i * BLK;
        const float4 g = gA[k];
        ((float4*)sA)[k] = (float4){-g.x, -g.y, -g.z, -g.w};
    }
    __syncthreads();

    // Half-norms: EXACT chain replicated in kernel B ((-a)*(-a) == a*a bitwise)
    {
        const float* na = &sA[tid * D_];
        float nr = na[0] * na[0];
        #pragma unroll
        for (int k = 1; k < D_; ++k) nr = fmaf(na[k], na[k], nr);
        sH[tid] = 0.5f * nr;
    }
    __syncthreads();

    // My RPT rows in registers (coalesced float4 loads)
    const int row0 = blockIdx.x * ROWS_PER_BLK + tid;
    float X[RPT][D_];
    #pragma unroll
    for (int r = 0; r < RPT; ++r) {
        const float4* px = (const float4*)(x + (size_t)(row0 + r * BLK) * D_);
        const float4 lo = px[0], hi = px[1];
        X[r][0] = lo.x; X[r][1] = lo.y; X[r][2] = lo.z; X[r][3] = lo.w;
        X[r][4] = hi.x; X[r][5] = hi.y; X[r][6] = hi.z; X[r][7] = hi.w;
    }

    float best[RPT];
    #pragma unroll
    for (int r = 0; r < RPT; ++r) best[r] = 3.4e38f;

    #pragma unroll 2
    for (int j = 0; j < MSPLIT; ++j) {
        const float4 a0 = ((const float4*)sA)[j * 2];     // LDS broadcast (free)
        const float4 a1 = ((const float4*)sA)[j * 2 + 1];
        const float  hn = sH[j];
        #pragma unroll
        for (int r = 0; r < RPT; ++r) {
            float s = fmaf(X[r][0], a0.x, hn);            // hn + sum x*(-a)
            s = fmaf(X[r][1], a0.y, s);
            s = fmaf(X[r][2], a0.z, s);
            s = fmaf(X[r][3], a0.w, s);
            s = fmaf(X[r][4], a1.x, s);
            s = fmaf(X[r][5], a1.y, s);
            s = fmaf(X[r][6], a1.z, s);
            s = fmaf(X[r][7], a1.w, s);
            best[r] = fminf(best[r], s);
        }
    }

    #pragma unroll
    for (int r = 0; r < RPT; ++r)
        ws[(size_t)split * ROWS + (row0 + r * BLK)] = best[r];   // coalesced
}

// Kernel B: 8 threads per row. Phase 1: reduce 32 split-minima -> winning
// (value, split) with lowest-split tie-break (== ascending strict '<').
// Phase 2: the 8 threads rescan the winning split (32 anchors each, lane-
// strided so 8 consecutive lanes read 8 consecutive anchors) with the
// bit-identical fmaf chain; min global index among bit-exact matches ==
// first occurrence == jnp.argmin tie-break. Phase 3: fused q_sample output.
__global__ __launch_bounds__(256) void refine_combine_kernel(
    const float* __restrict__ x,        // [ROWS][8]
    const float* __restrict__ anchors,  // [M_][8]
    const float* __restrict__ sa_tab,   // [1000]
    const float* __restrict__ sb_tab,   // [1000]
    const int*   __restrict__ t,        // [B_]
    const float* __restrict__ ws,       // [SPLITS][ROWS]
    float* __restrict__ out)            // [ROWS][8]
{
    const int tid  = threadIdx.x;
    const int g    = tid & (TPR - 1);   // lane within row-group
    const int rloc = tid >> 3;
    const int row  = blockIdx.x * BROWS + rloc;

    // Phase 1: per-thread scan of splits g, g+8, g+16, g+24 (ascending ->
    // strict '<' keeps lowest split within thread)
    float bs = 3.4e38f;
    int bsplit = 0;
    #pragma unroll
    for (int k = 0; k < SPLITS / TPR; ++k) {
        const int s = g + k * TPR;
        const float v = ws[(size_t)s * ROWS + row];
        const bool c = v < bs;
        bs     = c ? v : bs;
        bsplit = c ? s : bsplit;
    }
    // Cross-lane tuple-min over the 8-lane group (xor masks stay in-group)
    #pragma unroll
    for (int m = 1; m < TPR; m <<= 1) {
        const float ov  = __shfl_xor(bs, m);
        const int   osp = __shfl_xor(bsplit, m);
        const bool take = (ov < bs) || (ov == bs && osp < bsplit);
        bs     = take ? ov  : bs;
        bsplit = take ? osp : bsplit;
    }
    const uint32_t target = __float_as_uint(bs);
    const int base = bsplit * MSPLIT;

    // My row
    const float4* px = (const float4*)(x + (size_t)row * D_);
    const float4 xlo = px[0], xhi = px[1];
    const float X0 = xlo.x, X1 = xlo.y, X2 = xlo.z, X3 = xlo.w;
    const float X4 = xhi.x, X5 = xhi.y, X6 = xhi.z, X7 = xhi.w;

    // Phase 2: rescan winning split, lane-strided (coalesced within row-group)
    int mloc = 0x7FFFFFFF;
    #pragma unroll 4
    for (int j = 0; j < MSPLIT / TPR; ++j) {
        const int ai = base + j * TPR + g;
        const float4* pa = (const float4*)(anchors + (size_t)ai * D_);
        const float4 g0 = pa[0], g1 = pa[1];
        const float na0 = -g0.x, na1 = -g0.y, na2 = -g0.z, na3 = -g0.w;
        const float na4 = -g1.x, na5 = -g1.y, na6 = -g1.z, na7 = -g1.w;
        // hn chain — bit-identical to kernel A
        float nr = na0 * na0;
        nr = fmaf(na1, na1, nr);
        nr = fmaf(na2, na2, nr);
        nr = fmaf(na3, na3, nr);
        nr = fmaf(na4, na4, nr);
        nr = fmaf(na5, na5, nr);
        nr = fmaf(na6, na6, nr);
        nr = fmaf(na7, na7, nr);
        const float hn = 0.5f * nr;
        // score chain — bit-identical to kernel A
        float s = fmaf(X0, na0, hn);
        s = fmaf(X1, na1, s);
        s = fmaf(X2, na2, s);
        s = fmaf(X3, na3, s);
        s = fmaf(X4, na4, s);
        s = fmaf(X5, na5, s);
        s = fmaf(X6, na6, s);
        s = fmaf(X7, na7, s);
        const bool m = (__float_as_uint(s) == target);
        mloc = (m && ai < mloc) ? ai : mloc;   // ai ascending in j -> min = first
    }
    #pragma unroll
    for (int m = 1; m < TPR; m <<= 1) {
        const int o = __shfl_xor(mloc, m);
        mloc = (o < mloc) ? o : mloc;
    }
    const int bi = (mloc == 0x7FFFFFFF) ? base : mloc;  // defensive (cannot happen)

    // Phase 3: one lane per row writes the fused output
    if (g == 0) {
        const int b  = row >> 11;               // row / N_
        const int tb = t[b];
        const float sa = sa_tab[tb];
        const float sb = sb_tab[tb];

        const float4* pa = (const float4*)(anchors + (size_t)bi * D_);
        const float4 a0 = pa[0], a1 = pa[1];

        float4 o0, o1;
        o0.x = fmaf(sa, xlo.x, sb * a0.x);
        o0.y = fmaf(sa, xlo.y, sb * a0.y);
        o0.z = fmaf(sa, xlo.z, sb * a0.z);
        o0.w = fmaf(sa, xlo.w, sb * a0.w);
        o1.x = fmaf(sa, xhi.x, sb * a1.x);
        o1.y = fmaf(sa, xhi.y, sb * a1.y);
        o1.z = fmaf(sa, xhi.z, sb * a1.z);
        o1.w = fmaf(sa, xhi.w, sb * a1.w);

        float4* po = (float4*)(out + (size_t)row * D_);
        po[0] = o0;
        po[1] = o1;
    }
}

extern "C" void kernel_launch(void* const* d_in, const int* in_sizes, int n_in,
                              void* d_out, int out_size, void* d_ws, size_t ws_size,
                              hipStream_t stream) {
    const float* x       = (const float*)d_in[0];  // x_start [16,2048,4,2]
    const float* anchors = (const float*)d_in[1];  // anchors [8192,4,2]
    const float* sa_tab  = (const float*)d_in[2];  // sqrt_alphas_cumprod [1000]
    const float* sb_tab  = (const float*)d_in[3];  // sqrt_one_minus_alphas_cumprod [1000]
    const int*   t       = (const int*)d_in[4];    // t [16]
    float* out = (float*)d_out;

    float* ws = (float*)d_ws;   // [SPLITS][ROWS] = 4 MB, fully overwritten

    dim3 gridA(ROWBLKS, SPLITS);   // 16 x 32 = 512 blocks
    argmin_part_kernel<<<gridA, BLK, 0, stream>>>(x, anchors, ws);

    refine_combine_kernel<<<ROWS / BROWS, 256, 0, stream>>>(
        x, anchors, sa_tab, sb_tab, t, ws, out);
}